// Round 10
// baseline (179.611 us; speedup 1.0000x reference)
//
#include <hip/hip_runtime.h>
#include <hip/hip_bf16.h>
#include <math.h>

// Problem dims (fixed by the reference)
#define B_  64
#define S_  512
#define D_  1024
#define E2_ 1024
#define WROW (D_ + E2_)   // 2048, row stride of w_weight
#define NTILES 4          // D_ / BNE (256-wide n-tiles)

typedef __attribute__((ext_vector_type(8))) short bf16x8;
typedef __attribute__((ext_vector_type(4))) float f32x4;
typedef __attribute__((ext_vector_type(8))) unsigned short u16x8;

// round-to-nearest-even f32 -> bf16
__device__ __forceinline__ unsigned short f2bf(float f) {
    unsigned u = __float_as_uint(f);
    u = (u + 0x7FFFu + ((u >> 16) & 1u)) >> 16;
    return (unsigned short)u;
}

__device__ __forceinline__ float bf2f(unsigned short u) {
    return __uint_as_float((unsigned)u << 16);
}

__device__ __forceinline__ void load_lds16(const void* g, void* l) {
    __builtin_amdgcn_global_load_lds(
        (__attribute__((address_space(1))) void*)(void*)g,
        (__attribute__((address_space(3))) void*)l,
        16, 0, 0);
}

// branch-free tanh via v_exp_f32: tanh(x) = sign(x)*(e^{2|x|}-1)/(e^{2|x|}+1)
__device__ __forceinline__ float fast_tanh(float x) {
    float ax = fminf(fabsf(x), 16.0f);                       // tanh(16)==1.0f
    float t  = __builtin_amdgcn_exp2f(ax * 2.8853900817779268f); // e^{2ax}
    float r  = (t - 1.0f) * __builtin_amdgcn_rcpf(t + 1.0f);
    return copysignf(r, x);
}

// ---------------------------------------------------------------------------
// PREP kernel: merged conv_enc + conv_we + dec_proj (independent outputs).
// blocks [0, 4096)      : enc f32 -> bf16 (grid-stride, 8 elems/thread)
// blocks [4096, 5120)   : We column-slice -> dense bf16 (one k-row/block)
// blocks [5120, 6144)   : dec_proj t[b][k] (one k/block, coalesced dec reads)
// ---------------------------------------------------------------------------
#define PREP_ENC 4096
#define PREP_WE  (PREP_ENC + D_)
#define PREP_DEC (PREP_WE + D_)

__global__ __launch_bounds__(256) void prep_kernel(
        const float* __restrict__ enc,    // (B*S, E2) f32
        const float* __restrict__ w,      // (D, 2048)
        const float* __restrict__ dec,    // (B, D)
        const float* __restrict__ bias,   // (D)
        unsigned short* __restrict__ encb,// (B*S, E2) bf16
        unsigned short* __restrict__ web, // (D, E2) bf16
        float* __restrict__ t)            // (B, D)
{
    const int blk = blockIdx.x;
    const int tid = threadIdx.x;

    if (blk < PREP_ENC) {
        // ---- enc conversion ----
        const int n8 = (B_ * S_ * E2_) / 8;
        int i = blk * 256 + tid;
        const int stride = PREP_ENC * 256;
        for (; i < n8; i += stride) {
            float4 a = *reinterpret_cast<const float4*>(enc + (size_t)i * 8);
            float4 b = *reinterpret_cast<const float4*>(enc + (size_t)i * 8 + 4);
            u16x8 o;
            o[0] = f2bf(a.x); o[1] = f2bf(a.y); o[2] = f2bf(a.z); o[3] = f2bf(a.w);
            o[4] = f2bf(b.x); o[5] = f2bf(b.y); o[6] = f2bf(b.z); o[7] = f2bf(b.w);
            *reinterpret_cast<u16x8*>(encb + (size_t)i * 8) = o;
        }
    } else if (blk < PREP_WE) {
        // ---- We conversion ----
        const int k = blk - PREP_ENC;
        const int j = tid * 4;
        float4 a = *reinterpret_cast<const float4*>(w + (size_t)k * WROW + D_ + j);
        ushort4 o;
        o.x = f2bf(a.x); o.y = f2bf(a.y); o.z = f2bf(a.z); o.w = f2bf(a.w);
        *reinterpret_cast<ushort4*>(web + (size_t)k * E2_ + j) = o;
    } else {
        // ---- dec_proj: t[b][k] = dot(dec[b], Wd[k]) + bias[k] ----
        __shared__ float wrow[D_];
        __shared__ float red[256];
        const int k = blk - PREP_WE;
        const float* wr = w + (size_t)k * WROW;   // Wd row
        for (int i = tid; i < D_; i += 256) wrow[i] = wr[i];
        __syncthreads();

        const int b = tid >> 2;     // 0..63
        const int q = tid & 3;      // 0..3
        // interleaved d-walk: lanes (b, q=0..3) read consecutive f32 ->
        // coalesced 16B segments per b-group; wrow reads broadcast per q.
        const float* dp = dec + b * D_;
        float acc = 0.f;
        #pragma unroll 8
        for (int i = 0; i < 256; ++i)
            acc = fmaf(dp[i * 4 + q], wrow[i * 4 + q], acc);
        red[tid] = acc;
        __syncthreads();
        if (q == 0) {
            float s = red[tid] + red[tid + 1] + red[tid + 2] + red[tid + 3];
            t[b * D_ + k] = s + bias[k];
        }
    }
}

// ---------------------------------------------------------------------------
// Kernel B: 256x256 tile, BK=64, 8 waves (2 wm x 4 wn), 512 threads.
// R6-exact form (best measured: 84.9 µs, 0 bank conflicts).
// Double-buffered LDS, counted-vmcnt pipeline 2 K-tiles deep.
// LDS st-swizzled: logical (row r, byte kb) at phys r*128 + (kb^((r&7)<<4)),
// staged via global_load_lds (linear dest) with inverse-swizzled global src.
// XCD m-locality swizzle: 4 n-tile blocks of one m-tile -> same XCD.
// Fused epilogue: tanh + v-dot + cross-wave reduce -> att_part (B*S, 4).
// ---------------------------------------------------------------------------
#define BME 256
#define BNE 256
#define BKE 64
#define KT_ (E2_ / BKE)   // 16 K-tiles

__global__ __launch_bounds__(512, 2) void energy_mfma_kernel(
        const unsigned short* __restrict__ encb,  // (B*S, E2) bf16
        const unsigned short* __restrict__ web,   // (D, E2) bf16
        const float* __restrict__ t,              // (B, D)
        const float* __restrict__ v,              // (D)
        float* __restrict__ att_part)             // (B*S, NTILES)
{
    __shared__ __align__(16) unsigned short As[2][BME * BKE];  // 2 x 32 KB
    __shared__ __align__(16) unsigned short Bs[2][BNE * BKE];  // 2 x 32 KB
    __shared__ float tv_s[BNE];
    __shared__ float vv_s[BNE];
    __shared__ float red[4][BME];

    // XCD m-locality swizzle: 512 blocks = 128 mblk x 4 ntile.
    const int g     = blockIdx.x;
    const int mblk  = (g & 7) + 8 * (g >> 5);
    const int ntile = (g >> 3) & 3;

    const int m0 = mblk * BME;
    const int n0 = ntile * BNE;
    const int b  = m0 >> 9;                 // 256-row tile never spans batches
    const int tid = threadIdx.x;
    const int w   = tid >> 6;               // wave 0..7
    const int l   = tid & 63;
    const int wm  = w >> 2;                 // wave row (0..1) -> 128 m-rows
    const int wn  = w & 3;                  // wave col (0..3) -> 64 n-cols

    if (tid < BNE) {
        tv_s[tid] = t[b * D_ + n0 + tid];
        vv_s[tid] = v[n0 + tid];
    }

    // --- staging source address (inverse-swizzled global) ---
    const int lr8 = l >> 3;
    const int lk  = 8 * ((l & 7) ^ lr8);
    const unsigned short* gA = encb + (size_t)m0 * E2_;
    const unsigned short* gB = web  + (size_t)n0 * E2_;

    // --- frag read offsets ---
    const int rA = wm * 128 + (l & 15);
    const int rB = wn * 64 + (l & 15);
    const int kswz = (l & 7) << 4;
    const int khi  = (l >> 4) << 4;

    f32x4 acc[8][4] = {};

    // stage one K-tile (A+B, 8 loads/thread) into buffer bf
    auto stage = [&](int bf, int kt) {
        const int k0 = kt * BKE;
        #pragma unroll
        for (int r = 0; r < 4; ++r) {
            const int c = r * 8 + w;              // chunk 0..31
            const int row = c * 8 + lr8;          // 0..255
            load_lds16(gA + (size_t)row * E2_ + k0 + lk,
                       (char*)As[bf] + c * 1024);
            load_lds16(gB + (size_t)row * E2_ + k0 + lk,
                       (char*)Bs[bf] + c * 1024);
        }
    };

    // prologue: stage tiles 0 and 1 (16 loads/thread in flight)
    stage(0, 0);
    stage(1, 1);

    for (int kt = 0; kt < KT_; ++kt) {
        const int cur = kt & 1;
        // counted wait: tile kt's 8 loads retired, tile kt+1's 8 fly on
        if (kt + 1 < KT_) {
            asm volatile("s_waitcnt vmcnt(8)" ::: "memory");
        } else {
            asm volatile("s_waitcnt vmcnt(0)" ::: "memory");
        }
        __builtin_amdgcn_sched_barrier(0);
        __builtin_amdgcn_s_barrier();          // raw barrier: no auto-drain
        __builtin_amdgcn_sched_barrier(0);

        #pragma unroll
        for (int kk = 0; kk < 2; ++kk) {
            const int kb = (kk * 64 + khi) ^ kswz;
            bf16x8 a[8], bb[4];
            #pragma unroll
            for (int mi = 0; mi < 8; ++mi)
                a[mi] = *reinterpret_cast<const bf16x8*>(
                    (const char*)As[cur] + (rA + mi * 16) * 128 + kb);
            #pragma unroll
            for (int ni = 0; ni < 4; ++ni)
                bb[ni] = *reinterpret_cast<const bf16x8*>(
                    (const char*)Bs[cur] + (rB + ni * 16) * 128 + kb);
            __builtin_amdgcn_s_setprio(1);
            #pragma unroll
            for (int mi = 0; mi < 8; ++mi)
                #pragma unroll
                for (int ni = 0; ni < 4; ++ni)
                    acc[mi][ni] = __builtin_amdgcn_mfma_f32_16x16x32_bf16(
                        a[mi], bb[ni], acc[mi][ni], 0, 0, 0);
            __builtin_amdgcn_s_setprio(0);
        }

        __builtin_amdgcn_sched_barrier(0);
        __builtin_amdgcn_s_barrier();          // all waves done reading buf[cur]
        __builtin_amdgcn_sched_barrier(0);
        if (kt + 2 < KT_) stage(cur, kt + 2);  // overwrite freed buffer
    }

    // --- epilogue: tanh + v-dot, reduce over n ---
    // D frag mapping: col = l&15, row = (l>>4)*4 + j  [m89-verified]
    #pragma unroll
    for (int mi = 0; mi < 8; ++mi) {
        float P[4] = {0.f, 0.f, 0.f, 0.f};
        #pragma unroll
        for (int ni = 0; ni < 4; ++ni) {
            const int nl = wn * 64 + ni * 16 + (l & 15);
            const float tvv = tv_s[nl];
            const float vvv = vv_s[nl];
            #pragma unroll
            for (int j = 0; j < 4; ++j) {
                float e = fast_tanh(acc[mi][ni][j] + tvv);
                P[j] = fmaf(e, vvv, P[j]);
            }
        }
        #pragma unroll
        for (int j = 0; j < 4; ++j) {
            float p = P[j];
            p += __shfl_xor(p, 1);
            p += __shfl_xor(p, 2);
            p += __shfl_xor(p, 4);
            p += __shfl_xor(p, 8);
            if ((l & 15) == 0)
                red[wn][wm * 128 + mi * 16 + (l >> 4) * 4 + j] = p;
        }
    }
    __syncthreads();
    if (tid < BME)
        att_part[(size_t)(m0 + tid) * NTILES + ntile] =
            (red[0][tid] + red[1][tid]) + (red[2][tid] + red[3][tid]);
}

// ---------------------------------------------------------------------------
// Kernel C: reduce partials + masked softmax over s per batch. One block per b.
// ---------------------------------------------------------------------------
__global__ __launch_bounds__(256) void softmax_kernel(
        const float* __restrict__ att_part,  // (B*S, NTILES)
        const int* __restrict__ mask,        // (B, S)
        float* __restrict__ wout)            // (B, S)
{
    __shared__ float red[256];
    const int b = blockIdx.x;
    const int tid = threadIdx.x;

    float x0 = 0.f, x1 = 0.f;
    #pragma unroll
    for (int p = 0; p < NTILES; ++p) {
        x0 += att_part[(size_t)(b * S_ + tid) * NTILES + p];
        x1 += att_part[(size_t)(b * S_ + 256 + tid) * NTILES + p];
    }
    bool m0v = (mask[b * S_ + tid] != 0);
    bool m1v = (mask[b * S_ + 256 + tid] != 0);
    if (!m0v) x0 = -INFINITY;
    if (!m1v) x1 = -INFINITY;

    float m = fmaxf(x0, x1);
    red[tid] = m;
    __syncthreads();
    for (int o = 128; o > 0; o >>= 1) {
        if (tid < o) red[tid] = fmaxf(red[tid], red[tid + o]);
        __syncthreads();
    }
    m = red[0];
    __syncthreads();

    float e0 = m0v ? expf(x0 - m) : 0.f;
    float e1 = m1v ? expf(x1 - m) : 0.f;
    red[tid] = e0 + e1;
    __syncthreads();
    for (int o = 128; o > 0; o >>= 1) {
        if (tid < o) red[tid] += red[tid + o];
        __syncthreads();
    }
    const float inv = 1.f / red[0];
    wout[b * S_ + tid] = e0 * inv;
    wout[b * S_ + 256 + tid] = e1 * inv;
}

// ---------------------------------------------------------------------------
// Kernel D: out_part[sc][b][e] = sum_{s in chunk sc} wgt[b,s]*encb[b,s,e]
// bf16 enc read (halves traffic), 8 s-chunks of 64, 128 threads (e8 lanes).
// ---------------------------------------------------------------------------
__global__ __launch_bounds__(128) void attout_part_kernel(
        const float* __restrict__ wgt,            // (B, S)
        const unsigned short* __restrict__ encb,  // (B, S, E2) bf16
        float* __restrict__ out_part)             // (8, B, E2)
{
    __shared__ float wsm[64];
    const int b  = blockIdx.y;
    const int sc = blockIdx.x;            // 0..7
    const int tid = threadIdx.x;          // e8 index 0..127
    if (tid < 64) wsm[tid] = wgt[b * S_ + sc * 64 + tid];
    __syncthreads();

    const unsigned short* ep =
        encb + ((size_t)b * S_ + sc * 64) * E2_ + tid * 8;
    float acc[8] = {};
    #pragma unroll 4
    for (int s = 0; s < 64; ++s) {
        u16x8 e8 = *reinterpret_cast<const u16x8*>(ep + (size_t)s * E2_);
        const float ws = wsm[s];
        #pragma unroll
        for (int j = 0; j < 8; ++j)
            acc[j] = fmaf(ws, bf2f((unsigned short)e8[j]), acc[j]);
    }
    float* op = out_part + ((size_t)sc * B_ + b) * E2_ + tid * 8;
    #pragma unroll
    for (int j = 0; j < 8; ++j) op[j] = acc[j];
}

__global__ __launch_bounds__(256) void attout_reduce_kernel(
        const float* __restrict__ out_part,  // (8, B, E2)
        float* __restrict__ out)             // (B, E2)
{
    const int idx = blockIdx.x * 256 + threadIdx.x;   // float4 index
    const int n4 = (B_ * E2_) / 4;
    const float4* p = reinterpret_cast<const float4*>(out_part);
    float4 r = p[idx];
    #pragma unroll
    for (int c = 1; c < 8; ++c) {
        float4 q = p[idx + c * n4];
        r.x += q.x; r.y += q.y; r.z += q.z; r.w += q.w;
    }
    reinterpret_cast<float4*>(out)[idx] = r;
}

// ---------------------------------------------------------------------------
extern "C" void kernel_launch(void* const* d_in, const int* in_sizes, int n_in,
                              void* d_out, int out_size, void* d_ws, size_t ws_size,
                              hipStream_t stream) {
    const float* dec  = (const float*)d_in[0];   // (B, D)
    const float* enc  = (const float*)d_in[1];   // (B, S, E2)
    const int*   mask = (const int*)d_in[2];     // (B, S)
    const float* w    = (const float*)d_in[3];   // (D, D+E2)
    const float* bias = (const float*)d_in[4];   // (D)
    const float* v    = (const float*)d_in[5];   // (D)
    float* out = (float*)d_out;                  // (B, 1, E2)

    // workspace layout
    float* t_buf    = (float*)d_ws;                      // B*D          f32
    float* att_part = t_buf + B_ * D_;                   // B*S*NTILES   f32
    float* wgt_buf  = att_part + B_ * S_ * NTILES;       // B*S          f32
    float* out_part = wgt_buf + B_ * S_;                 // 8*B*E2       f32
    unsigned short* encb = (unsigned short*)(out_part + 8 * B_ * E2_); // bf16
    unsigned short* web  = encb + (size_t)B_ * S_ * E2_;               // bf16

    prep_kernel<<<PREP_DEC, 256, 0, stream>>>(enc, w, dec, bias, encb, web, t_buf);
    energy_mfma_kernel<<<512, 512, 0, stream>>>(encb, web, t_buf, v, att_part);
    softmax_kernel<<<B_, 256, 0, stream>>>(att_part, mask, wgt_buf);
    attout_part_kernel<<<dim3(8, B_), 128, 0, stream>>>(wgt_buf, encb, out_part);
    attout_reduce_kernel<<<(B_ * E2_ / 4) / 256, 256, 0, stream>>>(out_part, out);
}

// Round 11
// 143.148 us; speedup vs baseline: 1.2547x; 1.2547x over previous
//
#include <hip/hip_runtime.h>
#include <hip/hip_bf16.h>
#include <math.h>

// Problem dims (fixed by the reference)
#define B_  64
#define S_  512
#define D_  1024
#define E2_ 1024
#define WROW (D_ + E2_)   // 2048, row stride of w_weight
#define NTILES 4          // D_ / BNE (256-wide n-tiles)

typedef __attribute__((ext_vector_type(8))) short bf16x8;
typedef __attribute__((ext_vector_type(4))) float f32x4;
typedef __attribute__((ext_vector_type(8))) unsigned short u16x8;

// round-to-nearest-even f32 -> bf16 (scalar fallback for prep kernels)
__device__ __forceinline__ unsigned short f2bf(float f) {
    unsigned u = __float_as_uint(f);
    u = (u + 0x7FFFu + ((u >> 16) & 1u)) >> 16;
    return (unsigned short)u;
}

__device__ __forceinline__ void load_lds16(const void* g, void* l) {
    __builtin_amdgcn_global_load_lds(
        (__attribute__((address_space(1))) void*)(void*)g,
        (__attribute__((address_space(3))) void*)l,
        16, 0, 0);
}

// branch-free tanh via v_exp_f32: tanh(x) = sign(x)*(e^{2|x|}-1)/(e^{2|x|}+1)
__device__ __forceinline__ float fast_tanh(float x) {
    float ax = fminf(fabsf(x), 16.0f);                       // tanh(16)==1.0f
    float t  = __builtin_amdgcn_exp2f(ax * 2.8853900817779268f); // e^{2ax}
    float r  = (t - 1.0f) * __builtin_amdgcn_rcpf(t + 1.0f);
    return copysignf(r, x);
}

// ---------------------------------------------------------------------------
// Convert We = w[:, D_:] (strided in w) -> dense bf16 (D_ x E2_)
// ---------------------------------------------------------------------------
__global__ __launch_bounds__(256) void conv_we_kernel(
        const float* __restrict__ w, unsigned short* __restrict__ web)
{
    const int k = blockIdx.x;
    const int j = threadIdx.x * 4;
    float4 a = *reinterpret_cast<const float4*>(w + (size_t)k * WROW + D_ + j);
    ushort4 o;
    o.x = f2bf(a.x); o.y = f2bf(a.y); o.z = f2bf(a.z); o.w = f2bf(a.w);
    *reinterpret_cast<ushort4*>(web + (size_t)k * E2_ + j) = o;
}

// ---------------------------------------------------------------------------
// Kernel A: t[b][k] = sum_d dec[b,d] * W[k,d] + bias[k]   (Wd = w[:, :D]), f32
// ---------------------------------------------------------------------------
__global__ __launch_bounds__(256) void dec_proj_kernel(
        const float* __restrict__ dec,    // (B, D)
        const float* __restrict__ w,      // (D, 2048)
        const float* __restrict__ bias,   // (D)
        float* __restrict__ t)            // (B, D)
{
    __shared__ float wrow[D_];
    __shared__ float red[256];
    const int k = blockIdx.x;
    const int tid = threadIdx.x;

    const float* wr = w + (size_t)k * WROW;
    for (int i = tid; i < D_; i += 256) wrow[i] = wr[i];
    __syncthreads();

    const int b = tid >> 2;
    const int q = tid & 3;
    const float* dp = dec + b * D_ + q * 256;
    const float* wp = wrow + q * 256;
    float acc = 0.f;
    #pragma unroll 8
    for (int i = 0; i < 256; ++i) acc = fmaf(dp[i], wp[i], acc);
    red[tid] = acc;
    __syncthreads();
    if (q == 0) {
        float s = red[tid] + red[tid + 1] + red[tid + 2] + red[tid + 3];
        t[b * D_ + k] = s + bias[k];
    }
}

// ---------------------------------------------------------------------------
// Kernel B: 256x256 tile, BK=64, 8 waves (2 wm x 4 wn), 512 threads.
// FUSED f32->bf16 A conversion, full-tile prefetch distance:
//   av holds A-data for tile kt+1 across ALL of tile kt's compute:
//   kt: issueB(kt+1) | SB | MFMA kk0 | SB | writeA(kt+1) issueA(kt+2) | SB |
//       MFMA kk1 | SB | vmcnt(8) lgkmcnt(0) | s_barrier
//   vmcnt ledger: end-of-kt in-flight = B(kt+1)[4 oldest] + A(kt+2)[8] ->
//   vmcnt(8) retires exactly B(kt+1); kt=14 tail uses vmcnt(0); never more.
// cvt via v_cvt_pk_bf16_f32 (RNE, 2 f32/instr): 16 instrs/tile vs ~128 VALU.
// LDS layout: logical (row r, byte kb) at phys r*128 + (kb^((r&7)<<4));
// A ds_write applies the XOR on the write side (both-sides swizzle, rule 21).
// B staged via global_load_lds from bf16 web, inverse-swizzled global source.
// XCD m-locality swizzle: 4 n-tile blocks of one m-tile -> same XCD
// (3/4 of A reads are L2 hits -> prefetch distance covers latency).
// Fused epilogue: tanh + v-dot + cross-wave reduce -> att_part (B*S, 4).
// ---------------------------------------------------------------------------
#define BME 256
#define BNE 256
#define BKE 64
#define KT_ (E2_ / BKE)   // 16 K-tiles

__global__ __launch_bounds__(512, 2) void energy_mfma_kernel(
        const float* __restrict__ encf,           // (B*S, E2) f32
        const unsigned short* __restrict__ web,   // (D, E2) bf16
        const float* __restrict__ t,              // (B, D)
        const float* __restrict__ v,              // (D)
        float* __restrict__ att_part)             // (B*S, NTILES)
{
    __shared__ __align__(16) unsigned short As[2][BME * BKE];  // 2 x 32 KB
    __shared__ __align__(16) unsigned short Bs[2][BNE * BKE];  // 2 x 32 KB
    __shared__ float tv_s[BNE];
    __shared__ float vv_s[BNE];
    __shared__ float red[4][BME];

    // XCD m-locality swizzle: 512 blocks = 128 mblk x 4 ntile.
    const int g     = blockIdx.x;
    const int mblk  = (g & 7) + 8 * (g >> 5);
    const int ntile = (g >> 3) & 3;

    const int m0 = mblk * BME;
    const int n0 = ntile * BNE;
    const int b  = m0 >> 9;                 // 256-row tile never spans batches
    const int tid = threadIdx.x;
    const int w   = tid >> 6;               // wave 0..7
    const int l   = tid & 63;
    const int wm  = w >> 2;                 // wave row (0..1) -> 128 m-rows
    const int wn  = w & 3;                  // wave col (0..3) -> 64 n-cols

    if (tid < BNE) {
        tv_s[tid] = t[b * D_ + n0 + tid];
        vv_s[tid] = v[n0 + tid];
    }

    // --- A reg-staging geometry (f32 source, coalesced 16B/lane) ---
    // load i: row = i*32 + (tid>>4), f32 col = (tid&15)*4
    const int arow0 = tid >> 4;              // 0..31; row&7 == arow0&7
    const int acolb = (tid & 15) * 8;        // byte col in bf16 LDS row
    const int aswz  = (arow0 & 7) << 4;
    const float* gAf = encf + (size_t)m0 * E2_;

    // --- B staging source address (inverse-swizzled global, gload_lds) ---
    const int lr8 = l >> 3;
    const int lk  = 8 * ((l & 7) ^ lr8);
    const unsigned short* gB = web + (size_t)n0 * E2_;

    // --- frag read offsets ---
    const int rA = wm * 128 + (l & 15);
    const int rB = wn * 64 + (l & 15);
    const int kswz = (l & 7) << 4;
    const int khi  = (l >> 4) << 4;

    f32x4 acc[8][4] = {};
    float4 av[8];                            // tile-(kt+1) A data (32 VGPR)

    auto issueA = [&](int kt) {
        const int k0 = kt * BKE;
        #pragma unroll
        for (int i = 0; i < 8; ++i) {
            const int row = i * 32 + arow0;
            av[i] = *reinterpret_cast<const float4*>(
                gAf + (size_t)row * E2_ + k0 + (tid & 15) * 4);
        }
    };
    auto writeA = [&](int bf) {
        #pragma unroll
        for (int i = 0; i < 8; ++i) {
            const int row = i * 32 + arow0;
            unsigned p0, p1;
            asm("v_cvt_pk_bf16_f32 %0, %1, %2"
                : "=v"(p0) : "v"(av[i].x), "v"(av[i].y));
            asm("v_cvt_pk_bf16_f32 %0, %1, %2"
                : "=v"(p1) : "v"(av[i].z), "v"(av[i].w));
            uint2 o; o.x = p0; o.y = p1;
            *reinterpret_cast<uint2*>(
                (char*)As[bf] + row * 128 + (acolb ^ aswz)) = o;
        }
    };
    auto issueB = [&](int bf, int kt) {
        const int k0 = kt * BKE;
        #pragma unroll
        for (int r = 0; r < 4; ++r) {
            const int c = r * 8 + w;              // chunk 0..31
            const int row = c * 8 + lr8;          // 0..255
            load_lds16(gB + (size_t)row * E2_ + k0 + lk,
                       (char*)Bs[bf] + c * 1024);
        }
    };

    // prologue: tile 0 staged; av <- tile 1
    issueA(0);
    issueB(0, 0);
    writeA(0);               // auto vmcnt waits only the A loads
    issueA(1);
    asm volatile("s_waitcnt vmcnt(8) lgkmcnt(0)" ::: "memory"); // retire B(0)
    __builtin_amdgcn_s_barrier();
    __builtin_amdgcn_sched_barrier(0);

    for (int kt = 0; kt < KT_; ++kt) {
        const int cur = kt & 1;
        const int nxt = cur ^ 1;

        if (kt + 1 < KT_) issueB(nxt, kt + 1);
        __builtin_amdgcn_sched_barrier(0);

        {   // ---- MFMA kk0 ----
            const int kb = khi ^ kswz;
            bf16x8 a[8], bb[4];
            #pragma unroll
            for (int mi = 0; mi < 8; ++mi)
                a[mi] = *reinterpret_cast<const bf16x8*>(
                    (const char*)As[cur] + (rA + mi * 16) * 128 + kb);
            #pragma unroll
            for (int ni = 0; ni < 4; ++ni)
                bb[ni] = *reinterpret_cast<const bf16x8*>(
                    (const char*)Bs[cur] + (rB + ni * 16) * 128 + kb);
            __builtin_amdgcn_s_setprio(1);
            #pragma unroll
            for (int mi = 0; mi < 8; ++mi)
                #pragma unroll
                for (int ni = 0; ni < 4; ++ni)
                    acc[mi][ni] = __builtin_amdgcn_mfma_f32_16x16x32_bf16(
                        a[mi], bb[ni], acc[mi][ni], 0, 0, 0);
            __builtin_amdgcn_s_setprio(0);
        }
        __builtin_amdgcn_sched_barrier(0);

        if (kt + 1 < KT_) writeA(nxt);       // cvt_pk + ds_write (av ready)
        if (kt + 2 < KT_) issueA(kt + 2);    // refill av, full tile ahead
        __builtin_amdgcn_sched_barrier(0);

        {   // ---- MFMA kk1 ----
            const int kb = (64 + khi) ^ kswz;
            bf16x8 a[8], bb[4];
            #pragma unroll
            for (int mi = 0; mi < 8; ++mi)
                a[mi] = *reinterpret_cast<const bf16x8*>(
                    (const char*)As[cur] + (rA + mi * 16) * 128 + kb);
            #pragma unroll
            for (int ni = 0; ni < 4; ++ni)
                bb[ni] = *reinterpret_cast<const bf16x8*>(
                    (const char*)Bs[cur] + (rB + ni * 16) * 128 + kb);
            __builtin_amdgcn_s_setprio(1);
            #pragma unroll
            for (int mi = 0; mi < 8; ++mi)
                #pragma unroll
                for (int ni = 0; ni < 4; ++ni)
                    acc[mi][ni] = __builtin_amdgcn_mfma_f32_16x16x32_bf16(
                        a[mi], bb[ni], acc[mi][ni], 0, 0, 0);
            __builtin_amdgcn_s_setprio(0);
        }
        __builtin_amdgcn_sched_barrier(0);

        // end-of-kt: retire B(kt+1); keep A(kt+2) in flight; ds_writes visible
        if (kt + 2 < KT_) {
            asm volatile("s_waitcnt vmcnt(8) lgkmcnt(0)" ::: "memory");
        } else if (kt + 1 < KT_) {
            asm volatile("s_waitcnt vmcnt(0) lgkmcnt(0)" ::: "memory");
        }
        __builtin_amdgcn_s_barrier();
        __builtin_amdgcn_sched_barrier(0);
    }

    // --- epilogue: tanh + v-dot, reduce over n ---
    // D frag mapping: col = l&15, row = (l>>4)*4 + j  [m89-verified]
    #pragma unroll
    for (int mi = 0; mi < 8; ++mi) {
        float P[4] = {0.f, 0.f, 0.f, 0.f};
        #pragma unroll
        for (int ni = 0; ni < 4; ++ni) {
            const int nl = wn * 64 + ni * 16 + (l & 15);
            const float tvv = tv_s[nl];
            const float vvv = vv_s[nl];
            #pragma unroll
            for (int j = 0; j < 4; ++j) {
                float e = fast_tanh(acc[mi][ni][j] + tvv);
                P[j] = fmaf(e, vvv, P[j]);
            }
        }
        #pragma unroll
        for (int j = 0; j < 4; ++j) {
            float p = P[j];
            p += __shfl_xor(p, 1);
            p += __shfl_xor(p, 2);
            p += __shfl_xor(p, 4);
            p += __shfl_xor(p, 8);
            if ((l & 15) == 0)
                red[wn][wm * 128 + mi * 16 + (l >> 4) * 4 + j] = p;
        }
    }
    __syncthreads();
    if (tid < BME)
        att_part[(size_t)(m0 + tid) * NTILES + ntile] =
            (red[0][tid] + red[1][tid]) + (red[2][tid] + red[3][tid]);
}

// ---------------------------------------------------------------------------
// Kernel C: reduce partials + masked softmax over s per batch. One block per b.
// ---------------------------------------------------------------------------
__global__ __launch_bounds__(256) void softmax_kernel(
        const float* __restrict__ att_part,  // (B*S, NTILES)
        const int* __restrict__ mask,        // (B, S)
        float* __restrict__ wout)            // (B, S)
{
    __shared__ float red[256];
    const int b = blockIdx.x;
    const int tid = threadIdx.x;

    float x0 = 0.f, x1 = 0.f;
    #pragma unroll
    for (int p = 0; p < NTILES; ++p) {
        x0 += att_part[(size_t)(b * S_ + tid) * NTILES + p];
        x1 += att_part[(size_t)(b * S_ + 256 + tid) * NTILES + p];
    }
    bool m0v = (mask[b * S_ + tid] != 0);
    bool m1v = (mask[b * S_ + 256 + tid] != 0);
    if (!m0v) x0 = -INFINITY;
    if (!m1v) x1 = -INFINITY;

    float m = fmaxf(x0, x1);
    red[tid] = m;
    __syncthreads();
    for (int o = 128; o > 0; o >>= 1) {
        if (tid < o) red[tid] = fmaxf(red[tid], red[tid + o]);
        __syncthreads();
    }
    m = red[0];
    __syncthreads();

    float e0 = m0v ? expf(x0 - m) : 0.f;
    float e1 = m1v ? expf(x1 - m) : 0.f;
    red[tid] = e0 + e1;
    __syncthreads();
    for (int o = 128; o > 0; o >>= 1) {
        if (tid < o) red[tid] += red[tid + o];
        __syncthreads();
    }
    const float inv = 1.f / red[0];
    wout[b * S_ + tid] = e0 * inv;
    wout[b * S_ + 256 + tid] = e1 * inv;
}

// ---------------------------------------------------------------------------
// Kernel D: out_part[sc][b][e] = sum_{s in chunk sc} wgt[b,s]*enc[b,s,e]
// f32 enc, float4/lane, 8 s-chunks of 64 for occupancy; tiny reduce after.
// ---------------------------------------------------------------------------
__global__ __launch_bounds__(256) void attout_part_kernel(
        const float* __restrict__ wgt,    // (B, S)
        const float* __restrict__ enc,    // (B, S, E2) f32
        float* __restrict__ out_part)     // (8, B, E2)
{
    __shared__ float wsm[64];
    const int b  = blockIdx.y;
    const int sc = blockIdx.x;            // 0..7
    const int tid = threadIdx.x;          // e4 index, covers E2 = 256*4
    if (tid < 64) wsm[tid] = wgt[b * S_ + sc * 64 + tid];
    __syncthreads();

    const float4* ep = reinterpret_cast<const float4*>(
        enc + ((size_t)b * S_ + sc * 64) * E2_) + tid;
    float4 acc = {0.f, 0.f, 0.f, 0.f};
    #pragma unroll 8
    for (int s = 0; s < 64; ++s) {
        float4 e4 = ep[(size_t)s * (E2_ / 4)];
        const float ws = wsm[s];
        acc.x = fmaf(ws, e4.x, acc.x);
        acc.y = fmaf(ws, e4.y, acc.y);
        acc.z = fmaf(ws, e4.z, acc.z);
        acc.w = fmaf(ws, e4.w, acc.w);
    }
    reinterpret_cast<float4*>(out_part + ((size_t)sc * B_ + b) * E2_)[tid] = acc;
}

__global__ __launch_bounds__(256) void attout_reduce_kernel(
        const float* __restrict__ out_part,  // (8, B, E2)
        float* __restrict__ out)             // (B, E2)
{
    const int idx = blockIdx.x * 256 + threadIdx.x;   // float4 index
    const int n4 = (B_ * E2_) / 4;
    const float4* p = reinterpret_cast<const float4*>(out_part);
    float4 r = p[idx];
    #pragma unroll
    for (int c = 1; c < 8; ++c) {
        float4 q = p[idx + c * n4];
        r.x += q.x; r.y += q.y; r.z += q.z; r.w += q.w;
    }
    reinterpret_cast<float4*>(out)[idx] = r;
}

// ---------------------------------------------------------------------------
extern "C" void kernel_launch(void* const* d_in, const int* in_sizes, int n_in,
                              void* d_out, int out_size, void* d_ws, size_t ws_size,
                              hipStream_t stream) {
    const float* dec  = (const float*)d_in[0];   // (B, D)
    const float* enc  = (const float*)d_in[1];   // (B, S, E2)
    const int*   mask = (const int*)d_in[2];     // (B, S)
    const float* w    = (const float*)d_in[3];   // (D, D+E2)
    const float* bias = (const float*)d_in[4];   // (D)
    const float* v    = (const float*)d_in[5];   // (D)
    float* out = (float*)d_out;                  // (B, 1, E2)

    // workspace layout
    float* t_buf    = (float*)d_ws;                      // B*D          f32
    float* att_part = t_buf + B_ * D_;                   // B*S*NTILES   f32
    float* wgt_buf  = att_part + B_ * S_ * NTILES;       // B*S          f32
    float* out_part = wgt_buf + B_ * S_;                 // 8*B*E2       f32
    unsigned short* web = (unsigned short*)(out_part + 8 * B_ * E2_); // D*E2 bf16

    conv_we_kernel<<<D_, 256, 0, stream>>>(w, web);
    dec_proj_kernel<<<D_, 256, 0, stream>>>(dec, w, bias, t_buf);
    energy_mfma_kernel<<<512, 512, 0, stream>>>(enc, web, t_buf, v, att_part);
    softmax_kernel<<<B_, 256, 0, stream>>>(att_part, mask, wgt_buf);
    attout_part_kernel<<<dim3(8, B_), 256, 0, stream>>>(wgt_buf, enc, out_part);
    attout_reduce_kernel<<<(B_ * E2_ / 4) / 256, 256, 0, stream>>>(out_part, out);
}

// Round 12
// 141.519 us; speedup vs baseline: 1.2692x; 1.0115x over previous
//
#include <hip/hip_runtime.h>
#include <hip/hip_bf16.h>
#include <math.h>

// Problem dims (fixed by the reference)
#define B_  64
#define S_  512
#define D_  1024
#define E2_ 1024
#define WROW (D_ + E2_)   // 2048, row stride of w_weight
#define NTILES 4          // D_ / BNE (256-wide n-tiles)

typedef __attribute__((ext_vector_type(8))) short bf16x8;
typedef __attribute__((ext_vector_type(4))) float f32x4;
typedef __attribute__((ext_vector_type(8))) unsigned short u16x8;

// round-to-nearest-even f32 -> bf16 (scalar, prep kernel)
__device__ __forceinline__ unsigned short f2bf(float f) {
    unsigned u = __float_as_uint(f);
    u = (u + 0x7FFFu + ((u >> 16) & 1u)) >> 16;
    return (unsigned short)u;
}

__device__ __forceinline__ float bf2f(unsigned short u) {
    return __uint_as_float((unsigned)u << 16);
}

__device__ __forceinline__ void load_lds16(const void* g, void* l) {
    __builtin_amdgcn_global_load_lds(
        (__attribute__((address_space(1))) void*)(void*)g,
        (__attribute__((address_space(3))) void*)l,
        16, 0, 0);
}

// branch-free tanh via v_exp_f32: tanh(x) = sign(x)*(e^{2|x|}-1)/(e^{2|x|}+1)
__device__ __forceinline__ float fast_tanh(float x) {
    float ax = fminf(fabsf(x), 16.0f);                       // tanh(16)==1.0f
    float t  = __builtin_amdgcn_exp2f(ax * 2.8853900817779268f); // e^{2ax}
    float r  = (t - 1.0f) * __builtin_amdgcn_rcpf(t + 1.0f);
    return copysignf(r, x);
}

// ---------------------------------------------------------------------------
// PREP: merged conv_we (blocks [0,1024)) + dec_proj (blocks [1024,2048)).
// Both branches are similar register weight (no R10-style 12-VGPR collapse).
// ---------------------------------------------------------------------------
__global__ __launch_bounds__(256) void prep_kernel(
        const float* __restrict__ w,      // (D, 2048)
        const float* __restrict__ dec,    // (B, D)
        const float* __restrict__ bias,   // (D)
        unsigned short* __restrict__ web, // (D, E2) bf16
        float* __restrict__ t)            // (B, D)
{
    const int blk = blockIdx.x;
    const int tid = threadIdx.x;

    if (blk < D_) {
        // ---- conv_we: row k = blk ----
        const int k = blk;
        const int j = tid * 4;
        float4 a = *reinterpret_cast<const float4*>(w + (size_t)k * WROW + D_ + j);
        ushort4 o;
        o.x = f2bf(a.x); o.y = f2bf(a.y); o.z = f2bf(a.z); o.w = f2bf(a.w);
        *reinterpret_cast<ushort4*>(web + (size_t)k * E2_ + j) = o;
    } else {
        // ---- dec_proj: t[b][k] = dot(dec[b], Wd[k]) + bias[k] ----
        __shared__ float wrow[D_];
        __shared__ float red[256];
        const int k = blk - D_;
        const float* wr = w + (size_t)k * WROW;
        for (int i = tid; i < D_; i += 256) wrow[i] = wr[i];
        __syncthreads();

        const int b = tid >> 2;
        const int q = tid & 3;
        const float* dp = dec + b * D_ + q * 256;
        const float* wp = wrow + q * 256;
        float acc = 0.f;
        #pragma unroll 8
        for (int i = 0; i < 256; ++i) acc = fmaf(dp[i], wp[i], acc);
        red[tid] = acc;
        __syncthreads();
        if (q == 0) {
            float s = red[tid] + red[tid + 1] + red[tid + 2] + red[tid + 3];
            t[b * D_ + k] = s + bias[k];
        }
    }
}

// ---------------------------------------------------------------------------
// Kernel B: 256x256 tile, BK=64, 8 waves (2 wm x 4 wn), 512 threads.
// FUSED f32->bf16 A conversion (R11-proven schedule), plus: ntile==0 blocks
// side-write the converted bf16 A to global encb (attout then reads bf16,
// halving its HBM traffic; net HBM bytes unchanged, moved into a
// non-BW-bound kernel).
//   kt: issueB(kt+1) | SB | MFMA kk0 | SB | writeA(kt+1) issueA(kt+2) | SB |
//       MFMA kk1 | SB | vmcnt(8) lgkmcnt(0) | s_barrier
// cvt via v_cvt_pk_bf16_f32 (RNE). LDS: phys r*128 + (kb^((r&7)<<4)).
// XCD m-locality swizzle: 4 n-tile blocks of one m-tile -> same XCD.
// Fused epilogue: tanh + v-dot + cross-wave reduce -> att_part (B*S, 4).
// ---------------------------------------------------------------------------
#define BME 256
#define BNE 256
#define BKE 64
#define KT_ (E2_ / BKE)   // 16 K-tiles

__global__ __launch_bounds__(512) void energy_mfma_kernel(
        const float* __restrict__ encf,           // (B*S, E2) f32
        const unsigned short* __restrict__ web,   // (D, E2) bf16
        const float* __restrict__ t,              // (B, D)
        const float* __restrict__ v,              // (D)
        float* __restrict__ att_part,             // (B*S, NTILES)
        unsigned short* __restrict__ encb)        // (B*S, E2) bf16 side-out
{
    __shared__ __align__(16) unsigned short As[2][BME * BKE];  // 2 x 32 KB
    __shared__ __align__(16) unsigned short Bs[2][BNE * BKE];  // 2 x 32 KB
    __shared__ float tv_s[BNE];
    __shared__ float vv_s[BNE];
    __shared__ float red[4][BME];

    // XCD m-locality swizzle: 512 blocks = 128 mblk x 4 ntile.
    const int g     = blockIdx.x;
    const int mblk  = (g & 7) + 8 * (g >> 5);
    const int ntile = (g >> 3) & 3;

    const int m0 = mblk * BME;
    const int n0 = ntile * BNE;
    const int b  = m0 >> 9;                 // 256-row tile never spans batches
    const int tid = threadIdx.x;
    const int w   = tid >> 6;               // wave 0..7
    const int l   = tid & 63;
    const int wm  = w >> 2;                 // wave row (0..1) -> 128 m-rows
    const int wn  = w & 3;                  // wave col (0..3) -> 64 n-cols
    const bool do_store = (ntile == 0);     // 1/4 blocks write encb

    if (tid < BNE) {
        tv_s[tid] = t[b * D_ + n0 + tid];
        vv_s[tid] = v[n0 + tid];
    }

    // --- A reg-staging geometry (f32 source, coalesced 16B/lane) ---
    const int arow0 = tid >> 4;              // 0..31; row&7 == arow0&7
    const int acolb = (tid & 15) * 8;        // byte col in bf16 LDS row
    const int aswz  = (arow0 & 7) << 4;
    const float* gAf = encf + (size_t)m0 * E2_;
    unsigned short* gOut = encb + (size_t)m0 * E2_;

    // --- B staging source address (inverse-swizzled global, gload_lds) ---
    const int lr8 = l >> 3;
    const int lk  = 8 * ((l & 7) ^ lr8);
    const unsigned short* gB = web + (size_t)n0 * E2_;

    // --- frag read offsets ---
    const int rA = wm * 128 + (l & 15);
    const int rB = wn * 64 + (l & 15);
    const int kswz = (l & 7) << 4;
    const int khi  = (l >> 4) << 4;

    f32x4 acc[8][4] = {};
    float4 av[8];                            // tile-(kt+1) A data (32 VGPR)

    auto issueA = [&](int kt) {
        const int k0 = kt * BKE;
        #pragma unroll
        for (int i = 0; i < 8; ++i) {
            const int row = i * 32 + arow0;
            av[i] = *reinterpret_cast<const float4*>(
                gAf + (size_t)row * E2_ + k0 + (tid & 15) * 4);
        }
    };
    auto writeA = [&](int bf, int kt) {      // kt only for the side-store addr
        const int k0 = kt * BKE;
        #pragma unroll
        for (int i = 0; i < 8; ++i) {
            const int row = i * 32 + arow0;
            unsigned p0, p1;
            asm("v_cvt_pk_bf16_f32 %0, %1, %2"
                : "=v"(p0) : "v"(av[i].x), "v"(av[i].y));
            asm("v_cvt_pk_bf16_f32 %0, %1, %2"
                : "=v"(p1) : "v"(av[i].z), "v"(av[i].w));
            uint2 o; o.x = p0; o.y = p1;
            *reinterpret_cast<uint2*>(
                (char*)As[bf] + row * 128 + (acolb ^ aswz)) = o;
            if (do_store)
                *reinterpret_cast<uint2*>(
                    gOut + (size_t)row * E2_ + k0 + (tid & 15) * 4) = o;
        }
    };
    auto issueB = [&](int bf, int kt) {
        const int k0 = kt * BKE;
        #pragma unroll
        for (int r = 0; r < 4; ++r) {
            const int c = r * 8 + w;              // chunk 0..31
            const int row = c * 8 + lr8;          // 0..255
            load_lds16(gB + (size_t)row * E2_ + k0 + lk,
                       (char*)Bs[bf] + c * 1024);
        }
    };

    // prologue: tile 0 staged; av <- tile 1
    issueA(0);
    issueB(0, 0);
    writeA(0, 0);            // auto vmcnt waits only the A loads
    issueA(1);
    asm volatile("s_waitcnt vmcnt(8) lgkmcnt(0)" ::: "memory"); // retire B(0)
    __builtin_amdgcn_s_barrier();
    __builtin_amdgcn_sched_barrier(0);

    for (int kt = 0; kt < KT_; ++kt) {
        const int cur = kt & 1;
        const int nxt = cur ^ 1;

        if (kt + 1 < KT_) issueB(nxt, kt + 1);
        __builtin_amdgcn_sched_barrier(0);

        {   // ---- MFMA kk0 ----
            const int kb = khi ^ kswz;
            bf16x8 a[8], bb[4];
            #pragma unroll
            for (int mi = 0; mi < 8; ++mi)
                a[mi] = *reinterpret_cast<const bf16x8*>(
                    (const char*)As[cur] + (rA + mi * 16) * 128 + kb);
            #pragma unroll
            for (int ni = 0; ni < 4; ++ni)
                bb[ni] = *reinterpret_cast<const bf16x8*>(
                    (const char*)Bs[cur] + (rB + ni * 16) * 128 + kb);
            __builtin_amdgcn_s_setprio(1);
            #pragma unroll
            for (int mi = 0; mi < 8; ++mi)
                #pragma unroll
                for (int ni = 0; ni < 4; ++ni)
                    acc[mi][ni] = __builtin_amdgcn_mfma_f32_16x16x32_bf16(
                        a[mi], bb[ni], acc[mi][ni], 0, 0, 0);
            __builtin_amdgcn_s_setprio(0);
        }
        __builtin_amdgcn_sched_barrier(0);

        if (kt + 1 < KT_) writeA(nxt, kt + 1);  // cvt_pk + ds_write (+store)
        if (kt + 2 < KT_) issueA(kt + 2);       // refill av, full tile ahead
        __builtin_amdgcn_sched_barrier(0);

        {   // ---- MFMA kk1 ----
            const int kb = (64 + khi) ^ kswz;
            bf16x8 a[8], bb[4];
            #pragma unroll
            for (int mi = 0; mi < 8; ++mi)
                a[mi] = *reinterpret_cast<const bf16x8*>(
                    (const char*)As[cur] + (rA + mi * 16) * 128 + kb);
            #pragma unroll
            for (int ni = 0; ni < 4; ++ni)
                bb[ni] = *reinterpret_cast<const bf16x8*>(
                    (const char*)Bs[cur] + (rB + ni * 16) * 128 + kb);
            __builtin_amdgcn_s_setprio(1);
            #pragma unroll
            for (int mi = 0; mi < 8; ++mi)
                #pragma unroll
                for (int ni = 0; ni < 4; ++ni)
                    acc[mi][ni] = __builtin_amdgcn_mfma_f32_16x16x32_bf16(
                        a[mi], bb[ni], acc[mi][ni], 0, 0, 0);
            __builtin_amdgcn_s_setprio(0);
        }
        __builtin_amdgcn_sched_barrier(0);

        // end-of-kt: retire B(kt+1) (8 = A(kt+2) stays in flight); drain lgkm
        if (kt + 2 < KT_) {
            asm volatile("s_waitcnt vmcnt(8) lgkmcnt(0)" ::: "memory");
        } else if (kt + 1 < KT_) {
            asm volatile("s_waitcnt vmcnt(0) lgkmcnt(0)" ::: "memory");
        }
        __builtin_amdgcn_s_barrier();
        __builtin_amdgcn_sched_barrier(0);
    }

    // --- epilogue: tanh + v-dot, reduce over n ---
    // D frag mapping: col = l&15, row = (l>>4)*4 + j  [m89-verified]
    #pragma unroll
    for (int mi = 0; mi < 8; ++mi) {
        float P[4] = {0.f, 0.f, 0.f, 0.f};
        #pragma unroll
        for (int ni = 0; ni < 4; ++ni) {
            const int nl = wn * 64 + ni * 16 + (l & 15);
            const float tvv = tv_s[nl];
            const float vvv = vv_s[nl];
            #pragma unroll
            for (int j = 0; j < 4; ++j) {
                float e = fast_tanh(acc[mi][ni][j] + tvv);
                P[j] = fmaf(e, vvv, P[j]);
            }
        }
        #pragma unroll
        for (int j = 0; j < 4; ++j) {
            float p = P[j];
            p += __shfl_xor(p, 1);
            p += __shfl_xor(p, 2);
            p += __shfl_xor(p, 4);
            p += __shfl_xor(p, 8);
            if ((l & 15) == 0)
                red[wn][wm * 128 + mi * 16 + (l >> 4) * 4 + j] = p;
        }
    }
    __syncthreads();
    if (tid < BME)
        att_part[(size_t)(m0 + tid) * NTILES + ntile] =
            (red[0][tid] + red[1][tid]) + (red[2][tid] + red[3][tid]);
}

// ---------------------------------------------------------------------------
// Kernel C: fused softmax + partial weighted sum.
// Grid (8 s-chunks, B), 128 threads. Each block re-derives the full 512-wide
// masked softmax from att_part (8 KB, L2-hot; 8x redundant but trivial),
// then computes out_part[sc][b][e] = sum_{s in chunk} w_s * encb[b,s,e].
// ---------------------------------------------------------------------------
__global__ __launch_bounds__(128) void attout_sm_kernel(
        const float* __restrict__ att_part,       // (B*S, NTILES=4)
        const int* __restrict__ mask,             // (B, S)
        const unsigned short* __restrict__ encb,  // (B, S, E2) bf16
        float* __restrict__ out_part)             // (8, B, E2)
{
    __shared__ float wall[S_];
    __shared__ float red[128];
    const int b  = blockIdx.y;
    const int sc = blockIdx.x;            // 0..7
    const int tid = threadIdx.x;          // 0..127

    // ---- softmax over the full row (each thread owns s = tid + j*128) ----
    float x[4];
    bool mv[4];
    #pragma unroll
    for (int j = 0; j < 4; ++j) {
        const int s = tid + j * 128;
        float4 p = *reinterpret_cast<const float4*>(
            att_part + (size_t)(b * S_ + s) * NTILES);
        x[j] = (p.x + p.y) + (p.z + p.w);
        mv[j] = (mask[b * S_ + s] != 0);
        if (!mv[j]) x[j] = -INFINITY;
    }
    float m = fmaxf(fmaxf(x[0], x[1]), fmaxf(x[2], x[3]));
    red[tid] = m;
    __syncthreads();
    for (int o = 64; o > 0; o >>= 1) {
        if (tid < o) red[tid] = fmaxf(red[tid], red[tid + o]);
        __syncthreads();
    }
    m = red[0];
    __syncthreads();
    float e[4], esum = 0.f;
    #pragma unroll
    for (int j = 0; j < 4; ++j) {
        e[j] = mv[j] ? expf(x[j] - m) : 0.f;
        esum += e[j];
    }
    red[tid] = esum;
    __syncthreads();
    for (int o = 64; o > 0; o >>= 1) {
        if (tid < o) red[tid] += red[tid + o];
        __syncthreads();
    }
    const float inv = 1.f / red[0];
    #pragma unroll
    for (int j = 0; j < 4; ++j) wall[tid + j * 128] = e[j] * inv;
    __syncthreads();

    // ---- weighted sum over own 64-s chunk, e8 per lane ----
    const float* wsm = wall + sc * 64;
    const unsigned short* ep =
        encb + ((size_t)b * S_ + sc * 64) * E2_ + tid * 8;
    float acc[8] = {};
    #pragma unroll 4
    for (int s = 0; s < 64; ++s) {
        u16x8 e8 = *reinterpret_cast<const u16x8*>(ep + (size_t)s * E2_);
        const float ws = wsm[s];
        #pragma unroll
        for (int j = 0; j < 8; ++j)
            acc[j] = fmaf(ws, bf2f((unsigned short)e8[j]), acc[j]);
    }
    float* op = out_part + ((size_t)sc * B_ + b) * E2_ + tid * 8;
    #pragma unroll
    for (int j = 0; j < 8; ++j) op[j] = acc[j];
}

__global__ __launch_bounds__(256) void attout_reduce_kernel(
        const float* __restrict__ out_part,  // (8, B, E2)
        float* __restrict__ out)             // (B, E2)
{
    const int idx = blockIdx.x * 256 + threadIdx.x;   // float4 index
    const int n4 = (B_ * E2_) / 4;
    const float4* p = reinterpret_cast<const float4*>(out_part);
    float4 r = p[idx];
    #pragma unroll
    for (int c = 1; c < 8; ++c) {
        float4 q = p[idx + c * n4];
        r.x += q.x; r.y += q.y; r.z += q.z; r.w += q.w;
    }
    reinterpret_cast<float4*>(out)[idx] = r;
}

// ---------------------------------------------------------------------------
extern "C" void kernel_launch(void* const* d_in, const int* in_sizes, int n_in,
                              void* d_out, int out_size, void* d_ws, size_t ws_size,
                              hipStream_t stream) {
    const float* dec  = (const float*)d_in[0];   // (B, D)
    const float* enc  = (const float*)d_in[1];   // (B, S, E2)
    const int*   mask = (const int*)d_in[2];     // (B, S)
    const float* w    = (const float*)d_in[3];   // (D, D+E2)
    const float* bias = (const float*)d_in[4];   // (D)
    const float* v    = (const float*)d_in[5];   // (D)
    float* out = (float*)d_out;                  // (B, 1, E2)

    // workspace layout
    float* t_buf    = (float*)d_ws;                      // B*D          f32
    float* att_part = t_buf + B_ * D_;                   // B*S*NTILES   f32
    float* out_part = att_part + B_ * S_ * NTILES;       // 8*B*E2       f32
    unsigned short* web  = (unsigned short*)(out_part + 8 * B_ * E2_); // D*E2
    unsigned short* encb = web + (size_t)D_ * E2_;       // B*S*E2       bf16

    prep_kernel<<<2 * D_, 256, 0, stream>>>(w, dec, bias, web, t_buf);
    energy_mfma_kernel<<<512, 512, 0, stream>>>(enc, web, t_buf, v,
                                                att_part, encb);
    attout_sm_kernel<<<dim3(8, B_), 128, 0, stream>>>(att_part, mask,
                                                      encb, out_part);
    attout_reduce_kernel<<<(B_ * E2_ / 4) / 256, 256, 0, stream>>>(out_part, out);
}

// Round 13
// 137.695 us; speedup vs baseline: 1.3044x; 1.0278x over previous
//
#include <hip/hip_runtime.h>
#include <hip/hip_bf16.h>
#include <math.h>

// Problem dims (fixed by the reference)
#define B_  64
#define S_  512
#define D_  1024
#define E2_ 1024
#define WROW (D_ + E2_)   // 2048, row stride of w_weight
#define NTILES 4          // D_ / BNE (256-wide n-tiles)

typedef __attribute__((ext_vector_type(8))) short bf16x8;
typedef __attribute__((ext_vector_type(4))) float f32x4;
typedef __attribute__((ext_vector_type(8))) unsigned short u16x8;

// round-to-nearest-even f32 -> bf16 (scalar, prep kernel)
__device__ __forceinline__ unsigned short f2bf(float f) {
    unsigned u = __float_as_uint(f);
    u = (u + 0x7FFFu + ((u >> 16) & 1u)) >> 16;
    return (unsigned short)u;
}

__device__ __forceinline__ float bf2f(unsigned short u) {
    return __uint_as_float((unsigned)u << 16);
}

__device__ __forceinline__ void load_lds16(const void* g, void* l) {
    __builtin_amdgcn_global_load_lds(
        (__attribute__((address_space(1))) void*)(void*)g,
        (__attribute__((address_space(3))) void*)l,
        16, 0, 0);
}

// branch-free tanh via v_exp_f32: tanh(x) = sign(x)*(e^{2|x|}-1)/(e^{2|x|}+1)
__device__ __forceinline__ float fast_tanh(float x) {
    float ax = fminf(fabsf(x), 16.0f);                       // tanh(16)==1.0f
    float t  = __builtin_amdgcn_exp2f(ax * 2.8853900817779268f); // e^{2ax}
    float r  = (t - 1.0f) * __builtin_amdgcn_rcpf(t + 1.0f);
    return copysignf(r, x);
}

// ---------------------------------------------------------------------------
// PREP: merged conv_we (blocks [0,1024)) + dec_proj (blocks [1024,2048)).
// ---------------------------------------------------------------------------
__global__ __launch_bounds__(256) void prep_kernel(
        const float* __restrict__ w,      // (D, 2048)
        const float* __restrict__ dec,    // (B, D)
        const float* __restrict__ bias,   // (D)
        unsigned short* __restrict__ web, // (D, E2) bf16
        float* __restrict__ t)            // (B, D)
{
    const int blk = blockIdx.x;
    const int tid = threadIdx.x;

    if (blk < D_) {
        // ---- conv_we: row k = blk ----
        const int k = blk;
        const int j = tid * 4;
        float4 a = *reinterpret_cast<const float4*>(w + (size_t)k * WROW + D_ + j);
        ushort4 o;
        o.x = f2bf(a.x); o.y = f2bf(a.y); o.z = f2bf(a.z); o.w = f2bf(a.w);
        *reinterpret_cast<ushort4*>(web + (size_t)k * E2_ + j) = o;
    } else {
        // ---- dec_proj: t[b][k] = dot(dec[b], Wd[k]) + bias[k] ----
        __shared__ float wrow[D_];
        __shared__ float red[256];
        const int k = blk - D_;
        const float* wr = w + (size_t)k * WROW;
        for (int i = tid; i < D_; i += 256) wrow[i] = wr[i];
        __syncthreads();

        const int b = tid >> 2;
        const int q = tid & 3;
        const float* dp = dec + b * D_ + q * 256;
        const float* wp = wrow + q * 256;
        float acc = 0.f;
        #pragma unroll 8
        for (int i = 0; i < 256; ++i) acc = fmaf(dp[i], wp[i], acc);
        red[tid] = acc;
        __syncthreads();
        if (q == 0) {
            float s = red[tid] + red[tid + 1] + red[tid + 2] + red[tid + 3];
            t[b * D_ + k] = s + bias[k];
        }
    }
}

// ---------------------------------------------------------------------------
// Kernel B: 256x256 tile, BK=64, 8 waves (2 wm x 4 wn), 512 threads.
// FUSED f32->bf16 A conversion (R11-proven schedule). encb side-write is
// DISTRIBUTED: the block handling n-tile `ntile` stores K-tiles
// [4*ntile, 4*ntile+4) of its m-panel (kt>>2 == ntile, wave-uniform branch).
// 512 blocks x 131 KB instead of 128 blocks x 524 KB -> no stragglers.
//   kt: issueB(kt+1) | SB | MFMA kk0 | SB | writeA(kt+1) issueA(kt+2) | SB |
//       MFMA kk1 | SB | vmcnt(8) lgkmcnt(0) | s_barrier
// cvt via v_cvt_pk_bf16_f32 (RNE). LDS: phys r*128 + (kb^((r&7)<<4)).
// XCD m-locality swizzle: 4 n-tile blocks of one m-tile -> same XCD.
// Fused epilogue: tanh + v-dot + cross-wave reduce -> att_part (B*S, 4).
// ---------------------------------------------------------------------------
#define BME 256
#define BNE 256
#define BKE 64
#define KT_ (E2_ / BKE)   // 16 K-tiles

__global__ __launch_bounds__(512) void energy_mfma_kernel(
        const float* __restrict__ encf,           // (B*S, E2) f32
        const unsigned short* __restrict__ web,   // (D, E2) bf16
        const float* __restrict__ t,              // (B, D)
        const float* __restrict__ v,              // (D)
        float* __restrict__ att_part,             // (B*S, NTILES)
        unsigned short* __restrict__ encb)        // (B*S, E2) bf16 side-out
{
    __shared__ __align__(16) unsigned short As[2][BME * BKE];  // 2 x 32 KB
    __shared__ __align__(16) unsigned short Bs[2][BNE * BKE];  // 2 x 32 KB
    __shared__ float tv_s[BNE];
    __shared__ float vv_s[BNE];
    __shared__ float red[4][BME];

    // XCD m-locality swizzle: 512 blocks = 128 mblk x 4 ntile.
    const int g     = blockIdx.x;
    const int mblk  = (g & 7) + 8 * (g >> 5);
    const int ntile = (g >> 3) & 3;

    const int m0 = mblk * BME;
    const int n0 = ntile * BNE;
    const int b  = m0 >> 9;                 // 256-row tile never spans batches
    const int tid = threadIdx.x;
    const int w   = tid >> 6;               // wave 0..7
    const int l   = tid & 63;
    const int wm  = w >> 2;                 // wave row (0..1) -> 128 m-rows
    const int wn  = w & 3;                  // wave col (0..3) -> 64 n-cols

    if (tid < BNE) {
        tv_s[tid] = t[b * D_ + n0 + tid];
        vv_s[tid] = v[n0 + tid];
    }

    // --- A reg-staging geometry (f32 source, coalesced 16B/lane) ---
    const int arow0 = tid >> 4;              // 0..31; row&7 == arow0&7
    const int acolb = (tid & 15) * 8;        // byte col in bf16 LDS row
    const int aswz  = (arow0 & 7) << 4;
    const float* gAf = encf + (size_t)m0 * E2_;
    unsigned short* gOut = encb + (size_t)m0 * E2_;

    // --- B staging source address (inverse-swizzled global, gload_lds) ---
    const int lr8 = l >> 3;
    const int lk  = 8 * ((l & 7) ^ lr8);
    const unsigned short* gB = web + (size_t)n0 * E2_;

    // --- frag read offsets ---
    const int rA = wm * 128 + (l & 15);
    const int rB = wn * 64 + (l & 15);
    const int kswz = (l & 7) << 4;
    const int khi  = (l >> 4) << 4;

    f32x4 acc[8][4] = {};
    float4 av[8];                            // tile-(kt+1) A data (32 VGPR)

    auto issueA = [&](int kt) {
        const int k0 = kt * BKE;
        #pragma unroll
        for (int i = 0; i < 8; ++i) {
            const int row = i * 32 + arow0;
            av[i] = *reinterpret_cast<const float4*>(
                gAf + (size_t)row * E2_ + k0 + (tid & 15) * 4);
        }
    };
    auto writeA = [&](int bf, int kt) {
        const int k0 = kt * BKE;
        const bool st = ((kt >> 2) == ntile);   // distributed store quarter
        #pragma unroll
        for (int i = 0; i < 8; ++i) {
            const int row = i * 32 + arow0;
            unsigned p0, p1;
            asm("v_cvt_pk_bf16_f32 %0, %1, %2"
                : "=v"(p0) : "v"(av[i].x), "v"(av[i].y));
            asm("v_cvt_pk_bf16_f32 %0, %1, %2"
                : "=v"(p1) : "v"(av[i].z), "v"(av[i].w));
            uint2 o; o.x = p0; o.y = p1;
            *reinterpret_cast<uint2*>(
                (char*)As[bf] + row * 128 + (acolb ^ aswz)) = o;
            if (st)
                *reinterpret_cast<uint2*>(
                    gOut + (size_t)row * E2_ + k0 + (tid & 15) * 4) = o;
        }
    };
    auto issueB = [&](int bf, int kt) {
        const int k0 = kt * BKE;
        #pragma unroll
        for (int r = 0; r < 4; ++r) {
            const int c = r * 8 + w;              // chunk 0..31
            const int row = c * 8 + lr8;          // 0..255
            load_lds16(gB + (size_t)row * E2_ + k0 + lk,
                       (char*)Bs[bf] + c * 1024);
        }
    };

    // prologue: tile 0 staged; av <- tile 1
    issueA(0);
    issueB(0, 0);
    writeA(0, 0);            // auto vmcnt waits only the A loads
    issueA(1);
    asm volatile("s_waitcnt vmcnt(8) lgkmcnt(0)" ::: "memory"); // retire B(0)
    __builtin_amdgcn_s_barrier();
    __builtin_amdgcn_sched_barrier(0);

    for (int kt = 0; kt < KT_; ++kt) {
        const int cur = kt & 1;
        const int nxt = cur ^ 1;

        if (kt + 1 < KT_) issueB(nxt, kt + 1);
        __builtin_amdgcn_sched_barrier(0);

        {   // ---- MFMA kk0 ----
            const int kb = khi ^ kswz;
            bf16x8 a[8], bb[4];
            #pragma unroll
            for (int mi = 0; mi < 8; ++mi)
                a[mi] = *reinterpret_cast<const bf16x8*>(
                    (const char*)As[cur] + (rA + mi * 16) * 128 + kb);
            #pragma unroll
            for (int ni = 0; ni < 4; ++ni)
                bb[ni] = *reinterpret_cast<const bf16x8*>(
                    (const char*)Bs[cur] + (rB + ni * 16) * 128 + kb);
            __builtin_amdgcn_s_setprio(1);
            #pragma unroll
            for (int mi = 0; mi < 8; ++mi)
                #pragma unroll
                for (int ni = 0; ni < 4; ++ni)
                    acc[mi][ni] = __builtin_amdgcn_mfma_f32_16x16x32_bf16(
                        a[mi], bb[ni], acc[mi][ni], 0, 0, 0);
            __builtin_amdgcn_s_setprio(0);
        }
        __builtin_amdgcn_sched_barrier(0);

        if (kt + 1 < KT_) writeA(nxt, kt + 1);  // cvt_pk + ds_write (+store)
        if (kt + 2 < KT_) issueA(kt + 2);       // refill av, full tile ahead
        __builtin_amdgcn_sched_barrier(0);

        {   // ---- MFMA kk1 ----
            const int kb = (64 + khi) ^ kswz;
            bf16x8 a[8], bb[4];
            #pragma unroll
            for (int mi = 0; mi < 8; ++mi)
                a[mi] = *reinterpret_cast<const bf16x8*>(
                    (const char*)As[cur] + (rA + mi * 16) * 128 + kb);
            #pragma unroll
            for (int ni = 0; ni < 4; ++ni)
                bb[ni] = *reinterpret_cast<const bf16x8*>(
                    (const char*)Bs[cur] + (rB + ni * 16) * 128 + kb);
            __builtin_amdgcn_s_setprio(1);
            #pragma unroll
            for (int mi = 0; mi < 8; ++mi)
                #pragma unroll
                for (int ni = 0; ni < 4; ++ni)
                    acc[mi][ni] = __builtin_amdgcn_mfma_f32_16x16x32_bf16(
                        a[mi], bb[ni], acc[mi][ni], 0, 0, 0);
            __builtin_amdgcn_s_setprio(0);
        }
        __builtin_amdgcn_sched_barrier(0);

        // end-of-kt: retire B(kt+1) (8 = A(kt+2) stays in flight); drain lgkm
        if (kt + 2 < KT_) {
            asm volatile("s_waitcnt vmcnt(8) lgkmcnt(0)" ::: "memory");
        } else if (kt + 1 < KT_) {
            asm volatile("s_waitcnt vmcnt(0) lgkmcnt(0)" ::: "memory");
        }
        __builtin_amdgcn_s_barrier();
        __builtin_amdgcn_sched_barrier(0);
    }

    // --- epilogue: tanh + v-dot, reduce over n ---
    // D frag mapping: col = l&15, row = (l>>4)*4 + j  [m89-verified]
    #pragma unroll
    for (int mi = 0; mi < 8; ++mi) {
        float P[4] = {0.f, 0.f, 0.f, 0.f};
        #pragma unroll
        for (int ni = 0; ni < 4; ++ni) {
            const int nl = wn * 64 + ni * 16 + (l & 15);
            const float tvv = tv_s[nl];
            const float vvv = vv_s[nl];
            #pragma unroll
            for (int j = 0; j < 4; ++j) {
                float e = fast_tanh(acc[mi][ni][j] + tvv);
                P[j] = fmaf(e, vvv, P[j]);
            }
        }
        #pragma unroll
        for (int j = 0; j < 4; ++j) {
            float p = P[j];
            p += __shfl_xor(p, 1);
            p += __shfl_xor(p, 2);
            p += __shfl_xor(p, 4);
            p += __shfl_xor(p, 8);
            if ((l & 15) == 0)
                red[wn][wm * 128 + mi * 16 + (l >> 4) * 4 + j] = p;
        }
    }
    __syncthreads();
    if (tid < BME)
        att_part[(size_t)(m0 + tid) * NTILES + ntile] =
            (red[0][tid] + red[1][tid]) + (red[2][tid] + red[3][tid]);
}

// ---------------------------------------------------------------------------
// Kernel C: fused softmax + partial weighted sum.
// ---------------------------------------------------------------------------
__global__ __launch_bounds__(128) void attout_sm_kernel(
        const float* __restrict__ att_part,       // (B*S, NTILES=4)
        const int* __restrict__ mask,             // (B, S)
        const unsigned short* __restrict__ encb,  // (B, S, E2) bf16
        float* __restrict__ out_part)             // (8, B, E2)
{
    __shared__ float wall[S_];
    __shared__ float red[128];
    const int b  = blockIdx.y;
    const int sc = blockIdx.x;            // 0..7
    const int tid = threadIdx.x;          // 0..127

    // ---- softmax over the full row (each thread owns s = tid + j*128) ----
    float x[4];
    bool mv[4];
    #pragma unroll
    for (int j = 0; j < 4; ++j) {
        const int s = tid + j * 128;
        float4 p = *reinterpret_cast<const float4*>(
            att_part + (size_t)(b * S_ + s) * NTILES);
        x[j] = (p.x + p.y) + (p.z + p.w);
        mv[j] = (mask[b * S_ + s] != 0);
        if (!mv[j]) x[j] = -INFINITY;
    }
    float m = fmaxf(fmaxf(x[0], x[1]), fmaxf(x[2], x[3]));
    red[tid] = m;
    __syncthreads();
    for (int o = 64; o > 0; o >>= 1) {
        if (tid < o) red[tid] = fmaxf(red[tid], red[tid + o]);
        __syncthreads();
    }
    m = red[0];
    __syncthreads();
    float e[4], esum = 0.f;
    #pragma unroll
    for (int j = 0; j < 4; ++j) {
        e[j] = mv[j] ? expf(x[j] - m) : 0.f;
        esum += e[j];
    }
    red[tid] = esum;
    __syncthreads();
    for (int o = 64; o > 0; o >>= 1) {
        if (tid < o) red[tid] += red[tid + o];
        __syncthreads();
    }
    const float inv = 1.f / red[0];
    #pragma unroll
    for (int j = 0; j < 4; ++j) wall[tid + j * 128] = e[j] * inv;
    __syncthreads();

    // ---- weighted sum over own 64-s chunk, e8 per lane ----
    const float* wsm = wall + sc * 64;
    const unsigned short* ep =
        encb + ((size_t)b * S_ + sc * 64) * E2_ + tid * 8;
    float acc[8] = {};
    #pragma unroll 4
    for (int s = 0; s < 64; ++s) {
        u16x8 e8 = *reinterpret_cast<const u16x8*>(ep + (size_t)s * E2_);
        const float ws = wsm[s];
        #pragma unroll
        for (int j = 0; j < 8; ++j)
            acc[j] = fmaf(ws, bf2f((unsigned short)e8[j]), acc[j]);
    }
    float* op = out_part + ((size_t)sc * B_ + b) * E2_ + tid * 8;
    #pragma unroll
    for (int j = 0; j < 8; ++j) op[j] = acc[j];
}

__global__ __launch_bounds__(256) void attout_reduce_kernel(
        const float* __restrict__ out_part,  // (8, B, E2)
        float* __restrict__ out)             // (B, E2)
{
    const int idx = blockIdx.x * 256 + threadIdx.x;   // float4 index
    const int n4 = (B_ * E2_) / 4;
    const float4* p = reinterpret_cast<const float4*>(out_part);
    float4 r = p[idx];
    #pragma unroll
    for (int c = 1; c < 8; ++c) {
        float4 q = p[idx + c * n4];
        r.x += q.x; r.y += q.y; r.z += q.z; r.w += q.w;
    }
    reinterpret_cast<float4*>(out)[idx] = r;
}

// ---------------------------------------------------------------------------
extern "C" void kernel_launch(void* const* d_in, const int* in_sizes, int n_in,
                              void* d_out, int out_size, void* d_ws, size_t ws_size,
                              hipStream_t stream) {
    const float* dec  = (const float*)d_in[0];   // (B, D)
    const float* enc  = (const float*)d_in[1];   // (B, S, E2)
    const int*   mask = (const int*)d_in[2];     // (B, S)
    const float* w    = (const float*)d_in[3];   // (D, D+E2)
    const float* bias = (const float*)d_in[4];   // (D)
    const float* v    = (const float*)d_in[5];   // (D)
    float* out = (float*)d_out;                  // (B, 1, E2)

    // workspace layout
    float* t_buf    = (float*)d_ws;                      // B*D          f32
    float* att_part = t_buf + B_ * D_;                   // B*S*NTILES   f32
    float* out_part = att_part + B_ * S_ * NTILES;       // 8*B*E2       f32
    unsigned short* web  = (unsigned short*)(out_part + 8 * B_ * E2_); // D*E2
    unsigned short* encb = web + (size_t)D_ * E2_;       // B*S*E2       bf16

    prep_kernel<<<2 * D_, 256, 0, stream>>>(w, dec, bias, web, t_buf);
    energy_mfma_kernel<<<512, 512, 0, stream>>>(enc, web, t_buf, v,
                                                att_part, encb);
    attout_sm_kernel<<<dim3(8, B_), 128, 0, stream>>>(att_part, mask,
                                                      encb, out_part);
    attout_reduce_kernel<<<(B_ * E2_ / 4) / 256, 256, 0, stream>>>(out_part, out);
}

// Round 14
// 136.286 us; speedup vs baseline: 1.3179x; 1.0103x over previous
//
#include <hip/hip_runtime.h>
#include <hip/hip_bf16.h>
#include <math.h>

// Problem dims (fixed by the reference)
#define B_  64
#define S_  512
#define D_  1024
#define E2_ 1024
#define WROW (D_ + E2_)   // 2048, row stride of w_weight
#define NTILES 4          // D_ / BNE (256-wide n-tiles)

typedef __attribute__((ext_vector_type(8))) short bf16x8;
typedef __attribute__((ext_vector_type(4))) float f32x4;
typedef __attribute__((ext_vector_type(8))) unsigned short u16x8;

// round-to-nearest-even f32 -> bf16 (scalar, prep kernel)
__device__ __forceinline__ unsigned short f2bf(float f) {
    unsigned u = __float_as_uint(f);
    u = (u + 0x7FFFu + ((u >> 16) & 1u)) >> 16;
    return (unsigned short)u;
}

__device__ __forceinline__ float bf2f(unsigned short u) {
    return __uint_as_float((unsigned)u << 16);
}

__device__ __forceinline__ void load_lds16(const void* g, void* l) {
    __builtin_amdgcn_global_load_lds(
        (__attribute__((address_space(1))) void*)(void*)g,
        (__attribute__((address_space(3))) void*)l,
        16, 0, 0);
}

// branch-free tanh via v_exp_f32: tanh(x) = sign(x)*(e^{2|x|}-1)/(e^{2|x|}+1)
__device__ __forceinline__ float fast_tanh(float x) {
    float ax = fminf(fabsf(x), 16.0f);                       // tanh(16)==1.0f
    float t  = __builtin_amdgcn_exp2f(ax * 2.8853900817779268f); // e^{2ax}
    float r  = (t - 1.0f) * __builtin_amdgcn_rcpf(t + 1.0f);
    return copysignf(r, x);
}

// ---------------------------------------------------------------------------
// PREP: merged conv_we (blocks [0,1024)) + dec_proj (blocks [1024,2048)).
// ---------------------------------------------------------------------------
__global__ __launch_bounds__(256) void prep_kernel(
        const float* __restrict__ w,      // (D, 2048)
        const float* __restrict__ dec,    // (B, D)
        const float* __restrict__ bias,   // (D)
        unsigned short* __restrict__ web, // (D, E2) bf16
        float* __restrict__ t)            // (B, D)
{
    const int blk = blockIdx.x;
    const int tid = threadIdx.x;

    if (blk < D_) {
        // ---- conv_we: row k = blk ----
        const int k = blk;
        const int j = tid * 4;
        float4 a = *reinterpret_cast<const float4*>(w + (size_t)k * WROW + D_ + j);
        ushort4 o;
        o.x = f2bf(a.x); o.y = f2bf(a.y); o.z = f2bf(a.z); o.w = f2bf(a.w);
        *reinterpret_cast<ushort4*>(web + (size_t)k * E2_ + j) = o;
    } else {
        // ---- dec_proj: t[b][k] = dot(dec[b], Wd[k]) + bias[k] ----
        __shared__ float wrow[D_];
        __shared__ float red[256];
        const int k = blk - D_;
        const float* wr = w + (size_t)k * WROW;
        for (int i = tid; i < D_; i += 256) wrow[i] = wr[i];
        __syncthreads();

        const int b = tid >> 2;
        const int q = tid & 3;
        const float* dp = dec + b * D_ + q * 256;
        const float* wp = wrow + q * 256;
        float acc = 0.f;
        #pragma unroll 8
        for (int i = 0; i < 256; ++i) acc = fmaf(dp[i], wp[i], acc);
        red[tid] = acc;
        __syncthreads();
        if (q == 0) {
            float s = red[tid] + red[tid + 1] + red[tid + 2] + red[tid + 3];
            t[b * D_ + k] = s + bias[k];
        }
    }
}

// ---------------------------------------------------------------------------
// Kernel B: 256x256 tile, BK=64, 8 waves (2 wm x 4 wn), 512 threads.
// FUSED f32->bf16 A conversion (R11-proven schedule) + distributed encb
// side-write (block ntile stores K-tiles [4*ntile,4*ntile+4) of its m-panel).
// VMCNT LEDGER FIX (R13 post-mortem): global STORES increment vmcnt, so the
// end-of-kt counted wait must be vmcnt(16) on store-kts (A(kt+2) 8 loads +
// 8 stores in flight, retiring exactly B(kt+1)'s 4) — otherwise every
// store-kt forces a full store-drain on the critical path (+17 µs measured).
//   kt: issueB(kt+1) | SB | MFMA kk0 | SB | writeA(kt+1)[+st] issueA(kt+2)
//       | SB | MFMA kk1 | SB | vmcnt(8 or 16) lgkmcnt(0) | s_barrier
// cvt via v_cvt_pk_bf16_f32 (RNE). LDS: phys r*128 + (kb^((r&7)<<4)).
// XCD m-locality swizzle: 4 n-tile blocks of one m-tile -> same XCD.
// Fused epilogue: tanh + v-dot + cross-wave reduce -> att_part (B*S, 4).
// ---------------------------------------------------------------------------
#define BME 256
#define BNE 256
#define BKE 64
#define KT_ (E2_ / BKE)   // 16 K-tiles

__global__ __launch_bounds__(512) void energy_mfma_kernel(
        const float* __restrict__ encf,           // (B*S, E2) f32
        const unsigned short* __restrict__ web,   // (D, E2) bf16
        const float* __restrict__ t,              // (B, D)
        const float* __restrict__ v,              // (D)
        float* __restrict__ att_part,             // (B*S, NTILES)
        unsigned short* __restrict__ encb)        // (B*S, E2) bf16 side-out
{
    __shared__ __align__(16) unsigned short As[2][BME * BKE];  // 2 x 32 KB
    __shared__ __align__(16) unsigned short Bs[2][BNE * BKE];  // 2 x 32 KB
    __shared__ float tv_s[BNE];
    __shared__ float vv_s[BNE];
    __shared__ float red[4][BME];

    // XCD m-locality swizzle: 512 blocks = 128 mblk x 4 ntile.
    const int g     = blockIdx.x;
    const int mblk  = (g & 7) + 8 * (g >> 5);
    const int ntile = (g >> 3) & 3;

    const int m0 = mblk * BME;
    const int n0 = ntile * BNE;
    const int b  = m0 >> 9;                 // 256-row tile never spans batches
    const int tid = threadIdx.x;
    const int w   = tid >> 6;               // wave 0..7
    const int l   = tid & 63;
    const int wm  = w >> 2;                 // wave row (0..1) -> 128 m-rows
    const int wn  = w & 3;                  // wave col (0..3) -> 64 n-cols

    if (tid < BNE) {
        tv_s[tid] = t[b * D_ + n0 + tid];
        vv_s[tid] = v[n0 + tid];
    }

    // --- A reg-staging geometry (f32 source, coalesced 16B/lane) ---
    const int arow0 = tid >> 4;              // 0..31; row&7 == arow0&7
    const int acolb = (tid & 15) * 8;        // byte col in bf16 LDS row
    const int aswz  = (arow0 & 7) << 4;
    const float* gAf = encf + (size_t)m0 * E2_;
    unsigned short* gOut = encb + (size_t)m0 * E2_;

    // --- B staging source address (inverse-swizzled global, gload_lds) ---
    const int lr8 = l >> 3;
    const int lk  = 8 * ((l & 7) ^ lr8);
    const unsigned short* gB = web + (size_t)n0 * E2_;

    // --- frag read offsets ---
    const int rA = wm * 128 + (l & 15);
    const int rB = wn * 64 + (l & 15);
    const int kswz = (l & 7) << 4;
    const int khi  = (l >> 4) << 4;

    f32x4 acc[8][4] = {};
    float4 av[8];                            // tile-(kt+1) A data (32 VGPR)

    auto issueA = [&](int kt) {
        const int k0 = kt * BKE;
        #pragma unroll
        for (int i = 0; i < 8; ++i) {
            const int row = i * 32 + arow0;
            av[i] = *reinterpret_cast<const float4*>(
                gAf + (size_t)row * E2_ + k0 + (tid & 15) * 4);
        }
    };
    auto writeA = [&](int bf, int kt) {
        const int k0 = kt * BKE;
        const bool st = ((kt >> 2) == ntile);   // distributed store quarter
        #pragma unroll
        for (int i = 0; i < 8; ++i) {
            const int row = i * 32 + arow0;
            unsigned p0, p1;
            asm("v_cvt_pk_bf16_f32 %0, %1, %2"
                : "=v"(p0) : "v"(av[i].x), "v"(av[i].y));
            asm("v_cvt_pk_bf16_f32 %0, %1, %2"
                : "=v"(p1) : "v"(av[i].z), "v"(av[i].w));
            uint2 o; o.x = p0; o.y = p1;
            *reinterpret_cast<uint2*>(
                (char*)As[bf] + row * 128 + (acolb ^ aswz)) = o;
            if (st)
                *reinterpret_cast<uint2*>(
                    gOut + (size_t)row * E2_ + k0 + (tid & 15) * 4) = o;
        }
    };
    auto issueB = [&](int bf, int kt) {
        const int k0 = kt * BKE;
        #pragma unroll
        for (int r = 0; r < 4; ++r) {
            const int c = r * 8 + w;              // chunk 0..31
            const int row = c * 8 + lr8;          // 0..255
            load_lds16(gB + (size_t)row * E2_ + k0 + lk,
                       (char*)Bs[bf] + c * 1024);
        }
    };

    // prologue: tile 0 staged; av <- tile 1
    issueA(0);
    issueB(0, 0);
    writeA(0, 0);            // auto vmcnt waits only the A loads
    issueA(1);
    // retire B(0): in flight = B0[4] + (ntile==0 ? st[8] : 0) + A1[8]
    if (ntile == 0) {
        asm volatile("s_waitcnt vmcnt(16) lgkmcnt(0)" ::: "memory");
    } else {
        asm volatile("s_waitcnt vmcnt(8) lgkmcnt(0)" ::: "memory");
    }
    __builtin_amdgcn_s_barrier();
    __builtin_amdgcn_sched_barrier(0);

    for (int kt = 0; kt < KT_; ++kt) {
        const int cur = kt & 1;
        const int nxt = cur ^ 1;
        const bool st_now = (((kt + 1) >> 2) == ntile);  // writeA(kt+1) stores?

        if (kt + 1 < KT_) issueB(nxt, kt + 1);
        __builtin_amdgcn_sched_barrier(0);

        {   // ---- MFMA kk0 ----
            const int kb = khi ^ kswz;
            bf16x8 a[8], bb[4];
            #pragma unroll
            for (int mi = 0; mi < 8; ++mi)
                a[mi] = *reinterpret_cast<const bf16x8*>(
                    (const char*)As[cur] + (rA + mi * 16) * 128 + kb);
            #pragma unroll
            for (int ni = 0; ni < 4; ++ni)
                bb[ni] = *reinterpret_cast<const bf16x8*>(
                    (const char*)Bs[cur] + (rB + ni * 16) * 128 + kb);
            __builtin_amdgcn_s_setprio(1);
            #pragma unroll
            for (int mi = 0; mi < 8; ++mi)
                #pragma unroll
                for (int ni = 0; ni < 4; ++ni)
                    acc[mi][ni] = __builtin_amdgcn_mfma_f32_16x16x32_bf16(
                        a[mi], bb[ni], acc[mi][ni], 0, 0, 0);
            __builtin_amdgcn_s_setprio(0);
        }
        __builtin_amdgcn_sched_barrier(0);

        if (kt + 1 < KT_) writeA(nxt, kt + 1);  // cvt_pk + ds_write (+store)
        if (kt + 2 < KT_) issueA(kt + 2);       // refill av, full tile ahead
        __builtin_amdgcn_sched_barrier(0);

        {   // ---- MFMA kk1 ----
            const int kb = (64 + khi) ^ kswz;
            bf16x8 a[8], bb[4];
            #pragma unroll
            for (int mi = 0; mi < 8; ++mi)
                a[mi] = *reinterpret_cast<const bf16x8*>(
                    (const char*)As[cur] + (rA + mi * 16) * 128 + kb);
            #pragma unroll
            for (int ni = 0; ni < 4; ++ni)
                bb[ni] = *reinterpret_cast<const bf16x8*>(
                    (const char*)Bs[cur] + (rB + ni * 16) * 128 + kb);
            __builtin_amdgcn_s_setprio(1);
            #pragma unroll
            for (int mi = 0; mi < 8; ++mi)
                #pragma unroll
                for (int ni = 0; ni < 4; ++ni)
                    acc[mi][ni] = __builtin_amdgcn_mfma_f32_16x16x32_bf16(
                        a[mi], bb[ni], acc[mi][ni], 0, 0, 0);
            __builtin_amdgcn_s_setprio(0);
        }
        __builtin_amdgcn_sched_barrier(0);

        // end-of-kt: retire B(kt+1). In flight after wait:
        //   A(kt+2)[8] + (st_now ? stores[8] : 0)
        if (kt + 2 < KT_) {
            if (st_now) {
                asm volatile("s_waitcnt vmcnt(16) lgkmcnt(0)" ::: "memory");
            } else {
                asm volatile("s_waitcnt vmcnt(8) lgkmcnt(0)" ::: "memory");
            }
        } else if (kt + 1 < KT_) {
            // kt=14: no A(16) issued; in flight = B(15)[4] + (st? stores[8])
            if (st_now) {
                asm volatile("s_waitcnt vmcnt(8) lgkmcnt(0)" ::: "memory");
            } else {
                asm volatile("s_waitcnt vmcnt(0) lgkmcnt(0)" ::: "memory");
            }
        }
        __builtin_amdgcn_s_barrier();
        __builtin_amdgcn_sched_barrier(0);
    }

    // --- epilogue: tanh + v-dot, reduce over n ---
    // D frag mapping: col = l&15, row = (l>>4)*4 + j  [m89-verified]
    #pragma unroll
    for (int mi = 0; mi < 8; ++mi) {
        float P[4] = {0.f, 0.f, 0.f, 0.f};
        #pragma unroll
        for (int ni = 0; ni < 4; ++ni) {
            const int nl = wn * 64 + ni * 16 + (l & 15);
            const float tvv = tv_s[nl];
            const float vvv = vv_s[nl];
            #pragma unroll
            for (int j = 0; j < 4; ++j) {
                float e = fast_tanh(acc[mi][ni][j] + tvv);
                P[j] = fmaf(e, vvv, P[j]);
            }
        }
        #pragma unroll
        for (int j = 0; j < 4; ++j) {
            float p = P[j];
            p += __shfl_xor(p, 1);
            p += __shfl_xor(p, 2);
            p += __shfl_xor(p, 4);
            p += __shfl_xor(p, 8);
            if ((l & 15) == 0)
                red[wn][wm * 128 + mi * 16 + (l >> 4) * 4 + j] = p;
        }
    }
    __syncthreads();
    if (tid < BME)
        att_part[(size_t)(m0 + tid) * NTILES + ntile] =
            (red[0][tid] + red[1][tid]) + (red[2][tid] + red[3][tid]);
}

// ---------------------------------------------------------------------------
// Kernel C: fused softmax + partial weighted sum.
// ---------------------------------------------------------------------------
__global__ __launch_bounds__(128) void attout_sm_kernel(
        const float* __restrict__ att_part,       // (B*S, NTILES=4)
        const int* __restrict__ mask,             // (B, S)
        const unsigned short* __restrict__ encb,  // (B, S, E2) bf16
        float* __restrict__ out_part)             // (8, B, E2)
{
    __shared__ float wall[S_];
    __shared__ float red[128];
    const int b  = blockIdx.y;
    const int sc = blockIdx.x;            // 0..7
    const int tid = threadIdx.x;          // 0..127

    // ---- softmax over the full row (each thread owns s = tid + j*128) ----
    float x[4];
    bool mv[4];
    #pragma unroll
    for (int j = 0; j < 4; ++j) {
        const int s = tid + j * 128;
        float4 p = *reinterpret_cast<const float4*>(
            att_part + (size_t)(b * S_ + s) * NTILES);
        x[j] = (p.x + p.y) + (p.z + p.w);
        mv[j] = (mask[b * S_ + s] != 0);
        if (!mv[j]) x[j] = -INFINITY;
    }
    float m = fmaxf(fmaxf(x[0], x[1]), fmaxf(x[2], x[3]));
    red[tid] = m;
    __syncthreads();
    for (int o = 64; o > 0; o >>= 1) {
        if (tid < o) red[tid] = fmaxf(red[tid], red[tid + o]);
        __syncthreads();
    }
    m = red[0];
    __syncthreads();
    float e[4], esum = 0.f;
    #pragma unroll
    for (int j = 0; j < 4; ++j) {
        e[j] = mv[j] ? expf(x[j] - m) : 0.f;
        esum += e[j];
    }
    red[tid] = esum;
    __syncthreads();
    for (int o = 64; o > 0; o >>= 1) {
        if (tid < o) red[tid] += red[tid + o];
        __syncthreads();
    }
    const float inv = 1.f / red[0];
    #pragma unroll
    for (int j = 0; j < 4; ++j) wall[tid + j * 128] = e[j] * inv;
    __syncthreads();

    // ---- weighted sum over own 64-s chunk, e8 per lane ----
    const float* wsm = wall + sc * 64;
    const unsigned short* ep =
        encb + ((size_t)b * S_ + sc * 64) * E2_ + tid * 8;
    float acc[8] = {};
    #pragma unroll 4
    for (int s = 0; s < 64; ++s) {
        u16x8 e8 = *reinterpret_cast<const u16x8*>(ep + (size_t)s * E2_);
        const float ws = wsm[s];
        #pragma unroll
        for (int j = 0; j < 8; ++j)
            acc[j] = fmaf(ws, bf2f((unsigned short)e8[j]), acc[j]);
    }
    float* op = out_part + ((size_t)sc * B_ + b) * E2_ + tid * 8;
    #pragma unroll
    for (int j = 0; j < 8; ++j) op[j] = acc[j];
}

__global__ __launch_bounds__(256) void attout_reduce_kernel(
        const float* __restrict__ out_part,  // (8, B, E2)
        float* __restrict__ out)             // (B, E2)
{
    const int idx = blockIdx.x * 256 + threadIdx.x;   // float4 index
    const int n4 = (B_ * E2_) / 4;
    const float4* p = reinterpret_cast<const float4*>(out_part);
    float4 r = p[idx];
    #pragma unroll
    for (int c = 1; c < 8; ++c) {
        float4 q = p[idx + c * n4];
        r.x += q.x; r.y += q.y; r.z += q.z; r.w += q.w;
    }
    reinterpret_cast<float4*>(out)[idx] = r;
}

// ---------------------------------------------------------------------------
extern "C" void kernel_launch(void* const* d_in, const int* in_sizes, int n_in,
                              void* d_out, int out_size, void* d_ws, size_t ws_size,
                              hipStream_t stream) {
    const float* dec  = (const float*)d_in[0];   // (B, D)
    const float* enc  = (const float*)d_in[1];   // (B, S, E2)
    const int*   mask = (const int*)d_in[2];     // (B, S)
    const float* w    = (const float*)d_in[3];   // (D, D+E2)
    const float* bias = (const float*)d_in[4];   // (D)
    const float* v    = (const float*)d_in[5];   // (D)
    float* out = (float*)d_out;                  // (B, 1, E2)

    // workspace layout
    float* t_buf    = (float*)d_ws;                      // B*D          f32
    float* att_part = t_buf + B_ * D_;                   // B*S*NTILES   f32
    float* out_part = att_part + B_ * S_ * NTILES;       // 8*B*E2       f32
    unsigned short* web  = (unsigned short*)(out_part + 8 * B_ * E2_); // D*E2
    unsigned short* encb = web + (size_t)D_ * E2_;       // B*S*E2       bf16

    prep_kernel<<<2 * D_, 256, 0, stream>>>(w, dec, bias, web, t_buf);
    energy_mfma_kernel<<<512, 512, 0, stream>>>(enc, web, t_buf, v,
                                                att_part, encb);
    attout_sm_kernel<<<dim3(8, B_), 128, 0, stream>>>(att_part, mask,
                                                      encb, out_part);
    attout_reduce_kernel<<<(B_ * E2_ / 4) / 256, 256, 0, stream>>>(out_part, out);
}